// Round 8
// baseline (514.254 us; speedup 1.0000x reference)
//
#include <hip/hip_runtime.h>
#include <hip/hip_bf16.h>

typedef __bf16 bf16x8 __attribute__((ext_vector_type(8)));
typedef __bf16 bf16x4 __attribute__((ext_vector_type(4)));
typedef float  f32x4  __attribute__((ext_vector_type(4)));

#define LAYERS 16
#define DIM 64
#define NHID 256
#define BATCH 32768
#define MTILE 64
#define NBLOCKS (BATCH / MTILE)   // 512

// packed weight sizes in bf16 elements
#define W0P_PER 16384             // per (net,layer): 16 otiles * 2 ktiles * 512
#define W1P_PER 65536             // 16 otiles * 8 ktiles * 512
#define W2P_PER 16384             // 4 otiles * 8 ktiles * 512
#define W0P_TOT (32 * W0P_PER)    // 524288
#define W1P_TOT (32 * W1P_PER)    // 2097152
#define W2P_TOT (32 * W2P_PER)    // 524288
#define PACK_TOT (W0P_TOT + W1P_TOT + W2P_TOT)  // 3145728 bf16 = 6.29 MB

__device__ __forceinline__ bf16x8 ldw(const __bf16* p) { return *(const bf16x8*)p; }

// ---------------------------------------------------------------------------
// Pack kernel (unchanged from r7): analytic masks, MFMA fragment layout:
// per (net,layer,gemm): [otile][ktile][lane(64)][j(8)].
// ---------------------------------------------------------------------------
__global__ __launch_bounds__(256) void pack_weights(
    const float* __restrict__ lW0, const float* __restrict__ lW1, const float* __restrict__ lW2,
    const float* __restrict__ sW0, const float* __restrict__ sW1, const float* __restrict__ sW2,
    __bf16* __restrict__ ws)
{
    const long i = ((long)blockIdx.x * 256 + threadIdx.x) * 8;  // elem base
    const float* W; long src; int l, n, k, which;
    if (i < W0P_TOT) {
        int netl = (int)(i / W0P_PER), rem = (int)(i % W0P_PER);
        int net = netl >> 4; l = netl & 15;
        int nt = rem >> 10, kt = (rem >> 9) & 1, lane = (rem >> 3) & 63;
        n = nt * 16 + (lane & 15); k = kt * 32 + (lane >> 4) * 8;
        W = net ? sW0 : lW0; which = 0;
        src = (long)(l * 256 + n) * 64 + k;
    } else if (i < W0P_TOT + W1P_TOT) {
        long r = i - W0P_TOT;
        int netl = (int)(r / W1P_PER), rem = (int)(r % W1P_PER);
        int net = netl >> 4; l = netl & 15;
        int nt = rem >> 12, kt = (rem >> 9) & 7, lane = (rem >> 3) & 63;
        n = nt * 16 + (lane & 15); k = kt * 32 + (lane >> 4) * 8;
        W = net ? sW1 : lW1; which = 1;
        src = (long)(l * 256 + n) * 256 + k;
    } else {
        long r = i - W0P_TOT - W1P_TOT;
        int netl = (int)(r / W2P_PER), rem = (int)(r % W2P_PER);
        int net = netl >> 4; l = netl & 15;
        int nt = rem >> 12, kt = (rem >> 9) & 7, lane = (rem >> 3) & 63;
        n = nt * 16 + (lane & 15); k = kt * 32 + (lane >> 4) * 8;
        W = net ? sW2 : lW2; which = 2;
        src = (long)(l * 64 + n) * 256 + k;
    }
    f32x4 wa = *(const f32x4*)(W + src);
    f32x4 wb = *(const f32x4*)(W + src + 4);
    const int nm = n % 63;                   // mh(n) for which 0/1
    const int pn = (l & 1) ? 63 - n : n;     // perm(n) for which 2 (n < 64 there)
    bf16x8 o;
    #pragma unroll
    for (int j = 0; j < 8; ++j) {
        int kk = k + j;
        bool m;
        if (which == 0)      { int pk = (l & 1) ? 63 - kk : kk; m = (pk <= nm); }
        else if (which == 1) { m = ((kk % 63) <= nm); }
        else                 { m = ((kk % 63) < pn); }
        float v = (j < 4) ? wa[j] : wb[j - 4];
        o[j] = m ? (__bf16)v : (__bf16)0.0f;
    }
    *(bf16x8*)(ws + i) = o;
}

// ---------------------------------------------------------------------------
// Flow kernel, round 8: r7 structure and fragment maps, but LDS shrunk
// 73.7 -> 40 KB so FOUR independent blocks fit per CU (r1-r7 all had 2;
// the 38% no-issue time is block-wide barrier drain, which only other
// co-resident blocks can fill). buf2 eliminated: h1 is written IN PLACE
// over h0 — G2 keeps its accumulators across a "h0 reads done" barrier,
// then its epilogue overwrites the single 32 KB buffer. 8 barriers/layer:
//   B1 (ybf ready; also h1(net1,l-1) reads done)
//   per net: B2 (h0 ready), B3 (h0 reads done), B4 (h1 ready),
//            net0 only: B5 (h1 reads done, before net1's G1 epilogue)
// __launch_bounds__(256,4): 128-VGPR cap; prefetch trimmed to fit:
// wg1[8] (G1, loaded in G3), wg2a[4] (G2 kt0, loaded in G1), wg3[4]
// (G3 kt<4, loaded in G2).
// ---------------------------------------------------------------------------
__global__ void __launch_bounds__(256, 4)
flow_kernel(
    const float* __restrict__ u,
    const __bf16* __restrict__ wp,
    const float* __restrict__ lb0, const float* __restrict__ lb1, const float* __restrict__ lb2,
    const float* __restrict__ sb0, const float* __restrict__ sb1, const float* __restrict__ sb2,
    float* __restrict__ out)
{
    __shared__ __bf16 ybf[4 * 2 * 512];   // [bt][kt(2)][lane][8]   8 KB
    __shared__ __bf16 buf[4 * 8 * 512];   // [bt][kt(8)][lane][8]  32 KB (h0 then h1)

    const int tid  = threadIdx.x;
    const int wave = tid >> 6;        // 0..3
    const int lane = tid & 63;
    const int quad = lane >> 4;
    const int l16  = lane & 15;
    const int blk  = blockIdx.x;

    const int qh = quad >> 1;         // epilogue frag-lane sub-index
    const int qp = (quad & 1) * 4;    // epilogue j base

    const __bf16* w0p = wp;
    const __bf16* w1p = wp + W0P_TOT;
    const __bf16* w2p = wp + W0P_TOT + W1P_TOT;

    // y regs (D-layout): y[bt][r] = row (blk*64 + bt*16 + l16), dim (wave*16 + quad*4 + r)
    f32x4 y[4];
    #pragma unroll
    for (int bt = 0; bt < 4; ++bt)
        y[bt] = *(const f32x4*)(u + (long)(blk * MTILE + bt * 16 + l16) * DIM
                                  + wave * 16 + quad * 4);

    // y-staging fragment coords for this wave's dim chunk [wave*16, wave*16+16)
    const int ktY = wave >> 1;                          // ybf ktile
    const int flY = ((wave & 1) * 2 + qh) * 16 + l16;   // ybf frag-lane

    // prime: G1 weights for (net0, layer0) — wave's otiles are 4w..4w+3
    bf16x8 wg1[8];   // [ot][kt]
    #pragma unroll
    for (int ot = 0; ot < 4; ++ot)
        #pragma unroll
        for (int kt = 0; kt < 2; ++kt)
            wg1[ot * 2 + kt] = ldw(w0p + (long)((4 * wave + ot) * 2 + kt) * 512 + lane * 8);

    for (int l = 0; l < LAYERS; ++l) {
        // stage y -> bf16 B-fragments (one b64 write per bt)
        #pragma unroll
        for (int bt = 0; bt < 4; ++bt) {
            bf16x4 v;
            #pragma unroll
            for (int r = 0; r < 4; ++r) v[r] = (__bf16)y[bt][r];
            *(bf16x4*)&ybf[((bt * 2 + ktY) * 64 + flY) * 8 + qp] = v;
        }
        __syncthreads();  // B1: ybf ready; h1(net1, l-1) reads all done

        f32x4 locr[4], scr[4];

        #pragma unroll
        for (int net = 0; net < 2; ++net) {
            const __bf16* w1b = w1p + (long)(net * 16 + l) * W1P_PER;
            const __bf16* w2b = w2p + (long)(net * 16 + l) * W2P_PER;
            // next G1 slot: net0 -> (net1, l); net1 -> (net0, l+1). l=15/net1
            // lands on slot 16 (net1, l0): in-bounds, values unused.
            const __bf16* w0n = w0p + (long)(net == 0 ? 16 + l : l + 1) * W0P_PER;
            const float* b0 = (net ? sb0 : lb0) + l * 256;
            const float* b1 = (net ? sb1 : lb1) + l * 256;
            const float* b2 = (net ? sb2 : lb2) + l * 64;

            bf16x8 wg2a[4];   // G2 weights kt0 x ot 0..3

            // ---- G1: W0 (A, prefetched in wg1) x y (B=ybf frags) -> h0 frags
            {
                f32x4 acc[4][4];
                #pragma unroll
                for (int ot = 0; ot < 4; ++ot)
                    #pragma unroll
                    for (int bt = 0; bt < 4; ++bt)
                        acc[ot][bt] = (f32x4){0.f, 0.f, 0.f, 0.f};
                #pragma unroll
                for (int kt = 0; kt < 2; ++kt) {
                    bf16x8 bv[4];
                    #pragma unroll
                    for (int bt = 0; bt < 4; ++bt)
                        bv[bt] = *(const bf16x8*)&ybf[((bt * 2 + kt) * 64 + lane) * 8];
                    #pragma unroll
                    for (int ot = 0; ot < 4; ++ot)
                        #pragma unroll
                        for (int bt = 0; bt < 4; ++bt)
                            acc[ot][bt] = __builtin_amdgcn_mfma_f32_16x16x32_bf16(wg1[ot * 2 + kt], bv[bt], acc[ot][bt], 0, 0, 0);
                }
                // prefetch G2 kt=0 across the upcoming barrier
                #pragma unroll
                for (int ot = 0; ot < 4; ++ot)
                    wg2a[ot] = ldw(w1b + (long)((4 * wave + ot) * 8 + 0) * 512 + lane * 8);
                // epilogue: relu + bias -> buf (h0 fragments)
                // (for net1 this overwrites h1(net0): safe, B5 has passed)
                #pragma unroll
                for (int ot = 0; ot < 4; ++ot) {
                    f32x4 bias = *(const f32x4*)(b0 + (4 * wave + ot) * 16 + quad * 4);
                    const int kt1 = (4 * wave + ot) >> 1;
                    const int fl  = ((ot & 1) * 2 + qh) * 16 + l16;
                    #pragma unroll
                    for (int bt = 0; bt < 4; ++bt) {
                        bf16x4 v;
                        #pragma unroll
                        for (int r = 0; r < 4; ++r)
                            v[r] = (__bf16)fmaxf(acc[ot][bt][r] + bias[r], 0.f);
                        *(bf16x4*)&buf[((bt * 8 + kt1) * 64 + fl) * 8 + qp] = v;
                    }
                }
            }
            __syncthreads();  // B2: h0 ready

            bf16x8 wg3[4];    // G3 weights kt 0..3

            // ---- G2: W1 (A, kt0 prefetched) x h0 (B=buf frags) -> acc (held)
            f32x4 acc2[4][4];
            {
                #pragma unroll
                for (int ot = 0; ot < 4; ++ot)
                    #pragma unroll
                    for (int bt = 0; bt < 4; ++bt)
                        acc2[ot][bt] = (f32x4){0.f, 0.f, 0.f, 0.f};
                #pragma unroll
                for (int kt = 0; kt < 8; ++kt) {
                    bf16x8 aw[4];
                    #pragma unroll
                    for (int ot = 0; ot < 4; ++ot)
                        aw[ot] = (kt < 1) ? wg2a[ot]
                                          : ldw(w1b + (long)((4 * wave + ot) * 8 + kt) * 512 + lane * 8);
                    bf16x8 bv[4];
                    #pragma unroll
                    for (int bt = 0; bt < 4; ++bt)
                        bv[bt] = *(const bf16x8*)&buf[((bt * 8 + kt) * 64 + lane) * 8];
                    #pragma unroll
                    for (int ot = 0; ot < 4; ++ot)
                        #pragma unroll
                        for (int bt = 0; bt < 4; ++bt)
                            acc2[ot][bt] = __builtin_amdgcn_mfma_f32_16x16x32_bf16(aw[ot], bv[bt], acc2[ot][bt], 0, 0, 0);
                }
                // prefetch G3 kt<4 across B3/B4
                #pragma unroll
                for (int kt = 0; kt < 4; ++kt)
                    wg3[kt] = ldw(w2b + (long)(wave * 8 + kt) * 512 + lane * 8);
            }
            __syncthreads();  // B3: all h0 reads done — buf may be overwritten

            // ---- G2 epilogue: relu + bias -> buf (h1 fragments, IN PLACE)
            {
                #pragma unroll
                for (int ot = 0; ot < 4; ++ot) {
                    f32x4 bias = *(const f32x4*)(b1 + (4 * wave + ot) * 16 + quad * 4);
                    const int kt1 = (4 * wave + ot) >> 1;
                    const int fl  = ((ot & 1) * 2 + qh) * 16 + l16;
                    #pragma unroll
                    for (int bt = 0; bt < 4; ++bt) {
                        bf16x4 v;
                        #pragma unroll
                        for (int r = 0; r < 4; ++r)
                            v[r] = (__bf16)fmaxf(acc2[ot][bt][r] + bias[r], 0.f);
                        *(bf16x4*)&buf[((bt * 8 + kt1) * 64 + fl) * 8 + qp] = v;
                    }
                }
            }
            __syncthreads();  // B4: h1 ready

            // ---- G3: W2 (A, kt<4 prefetched) x h1 (B=buf frags) -> regs
            {
                f32x4 acc[4];
                #pragma unroll
                for (int bt = 0; bt < 4; ++bt)
                    acc[bt] = (f32x4){0.f, 0.f, 0.f, 0.f};
                #pragma unroll
                for (int kt = 0; kt < 8; ++kt) {
                    bf16x8 aw = (kt < 4) ? wg3[kt]
                                         : ldw(w2b + (long)(wave * 8 + kt) * 512 + lane * 8);
                    #pragma unroll
                    for (int bt = 0; bt < 4; ++bt) {
                        bf16x8 bv = *(const bf16x8*)&buf[((bt * 8 + kt) * 64 + lane) * 8];
                        acc[bt] = __builtin_amdgcn_mfma_f32_16x16x32_bf16(aw, bv, acc[bt], 0, 0, 0);
                    }
                }
                // prefetch next G1 weights (low-pressure region)
                #pragma unroll
                for (int ot = 0; ot < 4; ++ot)
                    #pragma unroll
                    for (int kt = 0; kt < 2; ++kt)
                        wg1[ot * 2 + kt] = ldw(w0n + (long)((4 * wave + ot) * 2 + kt) * 512 + lane * 8);
                f32x4 bias = *(const f32x4*)(b2 + wave * 16 + quad * 4);
                if (net == 0) {
                    #pragma unroll
                    for (int bt = 0; bt < 4; ++bt)
                        #pragma unroll
                        for (int r = 0; r < 4; ++r)
                            locr[bt][r] = acc[bt][r] + bias[r];
                } else {
                    #pragma unroll
                    for (int bt = 0; bt < 4; ++bt)
                        #pragma unroll
                        for (int r = 0; r < 4; ++r)
                            scr[bt][r] = acc[bt][r] + bias[r];
                }
            }
            if (net == 0) __syncthreads();  // B5: h1(net0) reads done before
                                            // net1's G1 epilogue overwrites buf
            // for net1, B1 of the next layer provides the same guarantee
        }

        // coupling update, pure registers: y = exp(-sc) * (y - loc)
        #pragma unroll
        for (int bt = 0; bt < 4; ++bt)
            #pragma unroll
            for (int r = 0; r < 4; ++r)
                y[bt][r] = __expf(-scr[bt][r]) * (y[bt][r] - locr[bt][r]);
        // next ybf write safe: ybf readers (both nets' G1 mfma) are behind
        // this layer's B2 barriers
    }

    #pragma unroll
    for (int bt = 0; bt < 4; ++bt)
        *(f32x4*)(out + (long)(blk * MTILE + bt * 16 + l16) * DIM
                      + wave * 16 + quad * 4) = y[bt];
}

extern "C" void kernel_launch(void* const* d_in, const int* in_sizes, int n_in,
                              void* d_out, int out_size, void* d_ws, size_t ws_size,
                              hipStream_t stream) {
    const float* u   = (const float*)d_in[0];
    const float* lW0 = (const float*)d_in[1];
    const float* lb0 = (const float*)d_in[2];
    const float* lW1 = (const float*)d_in[3];
    const float* lb1 = (const float*)d_in[4];
    const float* lW2 = (const float*)d_in[5];
    const float* lb2 = (const float*)d_in[6];
    const float* sW0 = (const float*)d_in[7];
    const float* sb0 = (const float*)d_in[8];
    const float* sW1 = (const float*)d_in[9];
    const float* sb1 = (const float*)d_in[10];
    const float* sW2 = (const float*)d_in[11];
    const float* sb2 = (const float*)d_in[12];
    // d_in[13..15] = M0,M1,M2 — masks computed analytically in pack_weights

    if (ws_size < (size_t)PACK_TOT * sizeof(__bf16)) return;
    __bf16* ws = (__bf16*)d_ws;

    pack_weights<<<PACK_TOT / 8 / 256, 256, 0, stream>>>(
        lW0, lW1, lW2, sW0, sW1, sW2, ws);
    flow_kernel<<<NBLOCKS, 256, 0, stream>>>(
        u, ws, lb0, lb1, lb2, sb0, sb1, sb2, (float*)d_out);
}

// Round 9
// 329.591 us; speedup vs baseline: 1.5603x; 1.5603x over previous
//
#include <hip/hip_runtime.h>
#include <hip/hip_bf16.h>

typedef __bf16 bf16x8 __attribute__((ext_vector_type(8)));
typedef __bf16 bf16x4 __attribute__((ext_vector_type(4)));
typedef float  f32x4  __attribute__((ext_vector_type(4)));

#define LAYERS 16
#define DIM 64
#define NHID 256
#define BATCH 32768
#define MTILE 64
#define NBLOCKS (BATCH / MTILE)   // 512

// packed weight sizes in bf16 elements
#define W0P_PER 16384             // per (net,layer): 16 otiles * 2 ktiles * 512
#define W1P_PER 65536             // 16 otiles * 8 ktiles * 512
#define W2P_PER 16384             // 4 otiles * 8 ktiles * 512
#define W0P_TOT (32 * W0P_PER)    // 524288
#define W1P_TOT (32 * W1P_PER)    // 2097152
#define W2P_TOT (32 * W2P_PER)    // 524288
#define PACK_TOT (W0P_TOT + W1P_TOT + W2P_TOT)  // 3145728 bf16 = 6.29 MB

__device__ __forceinline__ bf16x8 ldw(const __bf16* p) { return *(const bf16x8*)p; }

// ---------------------------------------------------------------------------
// Pack kernel (unchanged from r7): analytic masks, MFMA fragment layout:
// per (net,layer,gemm): [otile][ktile][lane(64)][j(8)].
// ---------------------------------------------------------------------------
__global__ __launch_bounds__(256) void pack_weights(
    const float* __restrict__ lW0, const float* __restrict__ lW1, const float* __restrict__ lW2,
    const float* __restrict__ sW0, const float* __restrict__ sW1, const float* __restrict__ sW2,
    __bf16* __restrict__ ws)
{
    const long i = ((long)blockIdx.x * 256 + threadIdx.x) * 8;  // elem base
    const float* W; long src; int l, n, k, which;
    if (i < W0P_TOT) {
        int netl = (int)(i / W0P_PER), rem = (int)(i % W0P_PER);
        int net = netl >> 4; l = netl & 15;
        int nt = rem >> 10, kt = (rem >> 9) & 1, lane = (rem >> 3) & 63;
        n = nt * 16 + (lane & 15); k = kt * 32 + (lane >> 4) * 8;
        W = net ? sW0 : lW0; which = 0;
        src = (long)(l * 256 + n) * 64 + k;
    } else if (i < W0P_TOT + W1P_TOT) {
        long r = i - W0P_TOT;
        int netl = (int)(r / W1P_PER), rem = (int)(r % W1P_PER);
        int net = netl >> 4; l = netl & 15;
        int nt = rem >> 12, kt = (rem >> 9) & 7, lane = (rem >> 3) & 63;
        n = nt * 16 + (lane & 15); k = kt * 32 + (lane >> 4) * 8;
        W = net ? sW1 : lW1; which = 1;
        src = (long)(l * 256 + n) * 256 + k;
    } else {
        long r = i - W0P_TOT - W1P_TOT;
        int netl = (int)(r / W2P_PER), rem = (int)(r % W2P_PER);
        int net = netl >> 4; l = netl & 15;
        int nt = rem >> 12, kt = (rem >> 9) & 7, lane = (rem >> 3) & 63;
        n = nt * 16 + (lane & 15); k = kt * 32 + (lane >> 4) * 8;
        W = net ? sW2 : lW2; which = 2;
        src = (long)(l * 64 + n) * 256 + k;
    }
    f32x4 wa = *(const f32x4*)(W + src);
    f32x4 wb = *(const f32x4*)(W + src + 4);
    const int nm = n % 63;                   // mh(n) for which 0/1
    const int pn = (l & 1) ? 63 - n : n;     // perm(n) for which 2 (n < 64 there)
    bf16x8 o;
    #pragma unroll
    for (int j = 0; j < 8; ++j) {
        int kk = k + j;
        bool m;
        if (which == 0)      { int pk = (l & 1) ? 63 - kk : kk; m = (pk <= nm); }
        else if (which == 1) { m = ((kk % 63) <= nm); }
        else                 { m = ((kk % 63) < pn); }
        float v = (j < 4) ? wa[j] : wb[j - 4];
        o[j] = m ? (__bf16)v : (__bf16)0.0f;
    }
    *(bf16x8*)(ws + i) = o;
}

// ---------------------------------------------------------------------------
// Flow kernel, round 9: r8's 40 KB in-place-h1 structure, but in the ONE
// register regime the allocator honors: __launch_bounds__(256, 2) (r6/r7
// granted 116/120, spill-free; every other hint collapsed to 64/32 + spill).
// Held state across B3 minimized: G2's accumulators are converted to packed
// bf16x4 epilogue values (bias+relu+cvt) BEFORE the barrier (32 VGPRs held
// instead of 64), so peak pressure fits the ~120 grant. With VGPR<=128 AND
// LDS=40KB, 4 blocks/CU fit -> 16 waves/CU in 4 independent barrier groups.
// Barriers (8/layer):
//   B1 (ybf ready; h1(net1,l-1) reads done)
//   per net: B2 (h0 ready), B3 (h0 reads done), B4 (h1 ready),
//            net0 only: B5 (h1 reads done before net1's G1 epilogue)
// ---------------------------------------------------------------------------
__global__ void __launch_bounds__(256, 2)
flow_kernel(
    const float* __restrict__ u,
    const __bf16* __restrict__ wp,
    const float* __restrict__ lb0, const float* __restrict__ lb1, const float* __restrict__ lb2,
    const float* __restrict__ sb0, const float* __restrict__ sb1, const float* __restrict__ sb2,
    float* __restrict__ out)
{
    __shared__ __bf16 ybf[4 * 2 * 512];   // [bt][kt(2)][lane][8]   8 KB
    __shared__ __bf16 buf[4 * 8 * 512];   // [bt][kt(8)][lane][8]  32 KB (h0 then h1)

    const int tid  = threadIdx.x;
    const int wave = tid >> 6;        // 0..3
    const int lane = tid & 63;
    const int quad = lane >> 4;
    const int l16  = lane & 15;
    const int blk  = blockIdx.x;

    const int qh = quad >> 1;         // epilogue frag-lane sub-index
    const int qp = (quad & 1) * 4;    // epilogue j base

    const __bf16* w0p = wp;
    const __bf16* w1p = wp + W0P_TOT;
    const __bf16* w2p = wp + W0P_TOT + W1P_TOT;

    // y regs (D-layout): y[bt][r] = row (blk*64 + bt*16 + l16), dim (wave*16 + quad*4 + r)
    f32x4 y[4];
    #pragma unroll
    for (int bt = 0; bt < 4; ++bt)
        y[bt] = *(const f32x4*)(u + (long)(blk * MTILE + bt * 16 + l16) * DIM
                                  + wave * 16 + quad * 4);

    // y-staging fragment coords for this wave's dim chunk [wave*16, wave*16+16)
    const int ktY = wave >> 1;                          // ybf ktile
    const int flY = ((wave & 1) * 2 + qh) * 16 + l16;   // ybf frag-lane

    // prime: G1 weights for (net0, layer0) — wave's otiles are 4w..4w+3
    bf16x8 wg1[8];   // [ot][kt]
    #pragma unroll
    for (int ot = 0; ot < 4; ++ot)
        #pragma unroll
        for (int kt = 0; kt < 2; ++kt)
            wg1[ot * 2 + kt] = ldw(w0p + (long)((4 * wave + ot) * 2 + kt) * 512 + lane * 8);

    for (int l = 0; l < LAYERS; ++l) {
        // stage y -> bf16 B-fragments (one b64 write per bt)
        #pragma unroll
        for (int bt = 0; bt < 4; ++bt) {
            bf16x4 v;
            #pragma unroll
            for (int r = 0; r < 4; ++r) v[r] = (__bf16)y[bt][r];
            *(bf16x4*)&ybf[((bt * 2 + ktY) * 64 + flY) * 8 + qp] = v;
        }
        __syncthreads();  // B1: ybf ready; h1(net1, l-1) reads all done

        f32x4 locr[4], scr[4];

        #pragma unroll
        for (int net = 0; net < 2; ++net) {
            const __bf16* w1b = w1p + (long)(net * 16 + l) * W1P_PER;
            const __bf16* w2b = w2p + (long)(net * 16 + l) * W2P_PER;
            // next G1 slot: net0 -> (net1, l); net1 -> (net0, l+1). l=15/net1
            // lands on slot 16 (net1, l0): in-bounds, values unused.
            const __bf16* w0n = w0p + (long)(net == 0 ? 16 + l : l + 1) * W0P_PER;
            const float* b0 = (net ? sb0 : lb0) + l * 256;
            const float* b1 = (net ? sb1 : lb1) + l * 256;
            const float* b2 = (net ? sb2 : lb2) + l * 64;

            bf16x8 wg2a[4];   // G2 weights kt0 x ot 0..3

            // ---- G1: W0 (A, prefetched in wg1) x y (B=ybf frags) -> h0 frags
            {
                f32x4 acc[4][4];
                #pragma unroll
                for (int ot = 0; ot < 4; ++ot)
                    #pragma unroll
                    for (int bt = 0; bt < 4; ++bt)
                        acc[ot][bt] = (f32x4){0.f, 0.f, 0.f, 0.f};
                #pragma unroll
                for (int kt = 0; kt < 2; ++kt) {
                    bf16x8 bv[4];
                    #pragma unroll
                    for (int bt = 0; bt < 4; ++bt)
                        bv[bt] = *(const bf16x8*)&ybf[((bt * 2 + kt) * 64 + lane) * 8];
                    #pragma unroll
                    for (int ot = 0; ot < 4; ++ot)
                        #pragma unroll
                        for (int bt = 0; bt < 4; ++bt)
                            acc[ot][bt] = __builtin_amdgcn_mfma_f32_16x16x32_bf16(wg1[ot * 2 + kt], bv[bt], acc[ot][bt], 0, 0, 0);
                }
                // prefetch G2 kt=0 across the upcoming barrier
                #pragma unroll
                for (int ot = 0; ot < 4; ++ot)
                    wg2a[ot] = ldw(w1b + (long)((4 * wave + ot) * 8 + 0) * 512 + lane * 8);
                // epilogue: relu + bias -> buf (h0 fragments)
                // (for net1 this overwrites h1(net0): safe, B5 has passed)
                #pragma unroll
                for (int ot = 0; ot < 4; ++ot) {
                    f32x4 bias = *(const f32x4*)(b0 + (4 * wave + ot) * 16 + quad * 4);
                    const int kt1 = (4 * wave + ot) >> 1;
                    const int fl  = ((ot & 1) * 2 + qh) * 16 + l16;
                    #pragma unroll
                    for (int bt = 0; bt < 4; ++bt) {
                        bf16x4 v;
                        #pragma unroll
                        for (int r = 0; r < 4; ++r)
                            v[r] = (__bf16)fmaxf(acc[ot][bt][r] + bias[r], 0.f);
                        *(bf16x4*)&buf[((bt * 8 + kt1) * 64 + fl) * 8 + qp] = v;
                    }
                }
            }
            __syncthreads();  // B2: h0 ready

            bf16x8 wg3[4];    // G3 weights kt 0..3
            bf16x4 hv[4][4];  // packed h1 epilogue values, held across B3 (32 VGPR)

            // ---- G2: W1 (A, kt0 prefetched) x h0 (B=buf frags) -> hv (packed)
            {
                f32x4 acc2[4][4];
                #pragma unroll
                for (int ot = 0; ot < 4; ++ot)
                    #pragma unroll
                    for (int bt = 0; bt < 4; ++bt)
                        acc2[ot][bt] = (f32x4){0.f, 0.f, 0.f, 0.f};
                #pragma unroll
                for (int kt = 0; kt < 8; ++kt) {
                    bf16x8 aw[4];
                    #pragma unroll
                    for (int ot = 0; ot < 4; ++ot)
                        aw[ot] = (kt < 1) ? wg2a[ot]
                                          : ldw(w1b + (long)((4 * wave + ot) * 8 + kt) * 512 + lane * 8);
                    bf16x8 bv[4];
                    #pragma unroll
                    for (int bt = 0; bt < 4; ++bt)
                        bv[bt] = *(const bf16x8*)&buf[((bt * 8 + kt) * 64 + lane) * 8];
                    #pragma unroll
                    for (int ot = 0; ot < 4; ++ot)
                        #pragma unroll
                        for (int bt = 0; bt < 4; ++bt)
                            acc2[ot][bt] = __builtin_amdgcn_mfma_f32_16x16x32_bf16(aw[ot], bv[bt], acc2[ot][bt], 0, 0, 0);
                }
                // fold bias+relu+cvt NOW so only 32 VGPRs of packed bf16 cross B3
                #pragma unroll
                for (int ot = 0; ot < 4; ++ot) {
                    f32x4 bias = *(const f32x4*)(b1 + (4 * wave + ot) * 16 + quad * 4);
                    #pragma unroll
                    for (int bt = 0; bt < 4; ++bt)
                        #pragma unroll
                        for (int r = 0; r < 4; ++r)
                            hv[ot][bt][r] = (__bf16)fmaxf(acc2[ot][bt][r] + bias[r], 0.f);
                }
                // prefetch G3 kt<4 across B3/B4
                #pragma unroll
                for (int kt = 0; kt < 4; ++kt)
                    wg3[kt] = ldw(w2b + (long)(wave * 8 + kt) * 512 + lane * 8);
            }
            __syncthreads();  // B3: all h0 reads done — buf may be overwritten

            // ---- write h1 fragments IN PLACE
            #pragma unroll
            for (int ot = 0; ot < 4; ++ot) {
                const int kt1 = (4 * wave + ot) >> 1;
                const int fl  = ((ot & 1) * 2 + qh) * 16 + l16;
                #pragma unroll
                for (int bt = 0; bt < 4; ++bt)
                    *(bf16x4*)&buf[((bt * 8 + kt1) * 64 + fl) * 8 + qp] = hv[ot][bt];
            }
            __syncthreads();  // B4: h1 ready

            // ---- G3: W2 (A, kt<4 prefetched) x h1 (B=buf frags) -> regs
            {
                f32x4 acc[4];
                #pragma unroll
                for (int bt = 0; bt < 4; ++bt)
                    acc[bt] = (f32x4){0.f, 0.f, 0.f, 0.f};
                #pragma unroll
                for (int kt = 0; kt < 8; ++kt) {
                    bf16x8 aw = (kt < 4) ? wg3[kt]
                                         : ldw(w2b + (long)(wave * 8 + kt) * 512 + lane * 8);
                    #pragma unroll
                    for (int bt = 0; bt < 4; ++bt) {
                        bf16x8 bv = *(const bf16x8*)&buf[((bt * 8 + kt) * 64 + lane) * 8];
                        acc[bt] = __builtin_amdgcn_mfma_f32_16x16x32_bf16(aw, bv, acc[bt], 0, 0, 0);
                    }
                }
                // prefetch next G1 weights (low-pressure region)
                #pragma unroll
                for (int ot = 0; ot < 4; ++ot)
                    #pragma unroll
                    for (int kt = 0; kt < 2; ++kt)
                        wg1[ot * 2 + kt] = ldw(w0n + (long)((4 * wave + ot) * 2 + kt) * 512 + lane * 8);
                f32x4 bias = *(const f32x4*)(b2 + wave * 16 + quad * 4);
                if (net == 0) {
                    #pragma unroll
                    for (int bt = 0; bt < 4; ++bt)
                        #pragma unroll
                        for (int r = 0; r < 4; ++r)
                            locr[bt][r] = acc[bt][r] + bias[r];
                } else {
                    #pragma unroll
                    for (int bt = 0; bt < 4; ++bt)
                        #pragma unroll
                        for (int r = 0; r < 4; ++r)
                            scr[bt][r] = acc[bt][r] + bias[r];
                }
            }
            if (net == 0) __syncthreads();  // B5: h1(net0) reads done before
                                            // net1's G1 epilogue overwrites buf
            // for net1, B1 of the next layer provides the same guarantee
        }

        // coupling update, pure registers: y = exp(-sc) * (y - loc)
        #pragma unroll
        for (int bt = 0; bt < 4; ++bt)
            #pragma unroll
            for (int r = 0; r < 4; ++r)
                y[bt][r] = __expf(-scr[bt][r]) * (y[bt][r] - locr[bt][r]);
        // next ybf write safe: ybf readers (both nets' G1 mfma) are behind
        // this layer's B2 barriers
    }

    #pragma unroll
    for (int bt = 0; bt < 4; ++bt)
        *(f32x4*)(out + (long)(blk * MTILE + bt * 16 + l16) * DIM
                      + wave * 16 + quad * 4) = y[bt];
}

extern "C" void kernel_launch(void* const* d_in, const int* in_sizes, int n_in,
                              void* d_out, int out_size, void* d_ws, size_t ws_size,
                              hipStream_t stream) {
    const float* u   = (const float*)d_in[0];
    const float* lW0 = (const float*)d_in[1];
    const float* lb0 = (const float*)d_in[2];
    const float* lW1 = (const float*)d_in[3];
    const float* lb1 = (const float*)d_in[4];
    const float* lW2 = (const float*)d_in[5];
    const float* lb2 = (const float*)d_in[6];
    const float* sW0 = (const float*)d_in[7];
    const float* sb0 = (const float*)d_in[8];
    const float* sW1 = (const float*)d_in[9];
    const float* sb1 = (const float*)d_in[10];
    const float* sW2 = (const float*)d_in[11];
    const float* sb2 = (const float*)d_in[12];
    // d_in[13..15] = M0,M1,M2 — masks computed analytically in pack_weights

    if (ws_size < (size_t)PACK_TOT * sizeof(__bf16)) return;
    __bf16* ws = (__bf16*)d_ws;

    pack_weights<<<PACK_TOT / 8 / 256, 256, 0, stream>>>(
        lW0, lW1, lW2, sW0, sW1, sW2, ws);
    flow_kernel<<<NBLOCKS, 256, 0, stream>>>(
        u, ws, lb0, lb1, lb2, sb0, sb1, sb2, (float*)d_out);
}